// Round 7
// baseline (1880.502 us; speedup 1.0000x reference)
//
#include <hip/hip_runtime.h>

#define NN 262144

typedef __attribute__((ext_vector_type(8))) short short8;
typedef __attribute__((ext_vector_type(4))) float f32x4;

__device__ __forceinline__ unsigned short f2b(float x){
  union { float f; unsigned int u; } c; c.f = x;
  unsigned int u = c.u;
  unsigned int r = (u + 0x7FFFu + ((u >> 16) & 1u)) >> 16;
  return (unsigned short)r;
}

// ---------------- precompute: Wfold = Wm@Wu, bias_r = K*bm@Wu + bu ----------------
__global__ void prep1(const float* __restrict__ Wm, const float* __restrict__ Wu,
                      const float* __restrict__ bm, const float* __restrict__ bu,
                      float* __restrict__ Wfold, float* __restrict__ bias_r)
{
  int j = threadIdx.x;          // 0..127
  int i = blockIdx.x;           // 0..128 (128 => bias row)
  if (i < 128){
    float s = 0.f;
    for (int k = 0; k < 128; ++k) s += Wm[i*128 + k] * Wu[k*128 + j];
    Wfold[i*128 + j] = s;
  } else {
    float s = bu[j];
    for (int m = 0; m < 128; ++m) s += 8.0f * bm[m] * Wu[m*128 + j];
    bias_r[j] = s;
  }
}

// ---------------- precompute: transposed, padded, bf16 weights + folded biases ----
__global__ void prep2(const float* __restrict__ W0, const float* __restrict__ b0,
                      const float* __restrict__ W1, const float* __restrict__ b1,
                      const float* __restrict__ W2, const float* __restrict__ b2,
                      const float* __restrict__ W3, const float* __restrict__ b3,
                      const float* __restrict__ Wfold, const float* __restrict__ bias_r,
                      unsigned short* __restrict__ W1t, unsigned short* __restrict__ W2t,
                      unsigned short* __restrict__ W3t, unsigned short* __restrict__ W4t,
                      float* __restrict__ c0p, float* __restrict__ b1p,
                      float* __restrict__ b2p, float* __restrict__ b3p)
{
  int g = blockIdx.x * 256 + threadIdx.x;
  if (g < 40960){                       // W1t: c = g%160, k = g/160
    int c = g % 160, k = g / 160;
    float v = 0.f;
    if (c < 132){
      if (k < 128) v = W0[k*132 + c];
      else {
        int i = k - 128; float s = 0.f;
        for (int m = 0; m < 128; ++m) s += Wfold[i*128 + m] * W0[(128 + m)*132 + c];
        v = s;
      }
    }
    W1t[c*256 + k] = f2b(v);
  } else if (g < 66560){                // W2t
    int idx = g - 40960; int c = idx % 160, k = idx / 160;
    float v = (c < 132 && k < 132) ? W1[k*132 + c] : 0.f;
    W2t[c*160 + k] = f2b(v);
  } else if (g < 92160){                // W3t
    int idx = g - 66560; int c = idx % 160, k = idx / 160;
    float v = (c < 132 && k < 132) ? W2[k*132 + c] : 0.f;
    W3t[c*160 + k] = f2b(v);
  } else if (g < 112640){               // W4t [128][160]
    int idx = g - 92160; int c = idx & 127, k = idx >> 7;
    float v = (k < 132) ? W3[k*128 + c] : 0.f;
    W4t[c*160 + k] = f2b(v);
  } else if (g < 113248){               // biases
    int idx = g - 112640;
    if (idx < 160){
      int c = idx; float v = 0.f;
      if (c < 132){
        float s = b0[c];
        for (int k = 0; k < 128; ++k) s += bias_r[k] * W0[(128 + k)*132 + c];
        v = s;
      }
      c0p[c] = v;
    } else if (idx < 320){ int c = idx - 160; b1p[c] = (c < 132) ? b1[c] : 0.f; }
    else if (idx < 480){ int c = idx - 320; b2p[c] = (c < 132) ? b2[c] : 0.f; }
    else               { int c = idx - 480; b3p[c] = b3[c]; }
  }
}

// ---------------- producer/consumer fused kernel ----------------
// 512 blocks x 512 threads (8 waves), 512 nodes per block = 32 patches of 16.
// LDS ring: 8 slots x [16 rows][256 bf16] (8 KiB, XOR swizzle byte^=(row&7)<<4)
// + per-slot flag.  Waves 0..4 = producers (stream sig+comp, fill slots);
// waves 5..7 = consumers (R6-proven 4-layer MFMA chain per patch, in-place).
// Flag protocol per slot s, patch t (s = t%8): producer waits flags[s]==2*(t/8),
// fills, sets 2*(t/8)+1; consumer waits that, chains, sets 2*(t/8)+2.
// Static patch->wave assignment; all waves co-resident -> no deadlock.

#define NPROD 5
#define NCONS 3
#define RING  8
#define PATCHES 32

__device__ __forceinline__ int pidx(int row, int colByte){
  return (row*512 + (colByte ^ ((row & 7) << 4))) >> 1;   // ushort index
}

template<int KD, int NT, bool RELU>
__device__ __forceinline__ void layer_p(unsigned short* __restrict__ patch,
                                        int n, int lg,
                                        const unsigned short* __restrict__ Wt,
                                        const float* __restrict__ bias)
{
  constexpr int KS = KD / 32;
  short8 bf[KS];
  #pragma unroll
  for (int ks = 0; ks < KS; ++ks)
    bf[ks] = *(const short8*)&patch[pidx(n, ks*64 + lg*16)];

  #pragma unroll
  for (int c = 0; c < NT; c += 2){
    short8 wa[KS], wb[KS];
    #pragma unroll
    for (int ks = 0; ks < KS; ++ks){
      wa[ks] = *(const short8*)&Wt[(c*16 + n)*KD + ks*32 + lg*8];
      wb[ks] = *(const short8*)&Wt[((c+1)*16 + n)*KD + ks*32 + lg*8];
    }
    f32x4 aa = (f32x4){0.f,0.f,0.f,0.f};
    f32x4 ab = (f32x4){0.f,0.f,0.f,0.f};
    #pragma unroll
    for (int ks = 0; ks < KS; ++ks){
      aa = __builtin_amdgcn_mfma_f32_16x16x32_bf16(wa[ks], bf[ks], aa, 0, 0, 0);
      ab = __builtin_amdgcn_mfma_f32_16x16x32_bf16(wb[ks], bf[ks], ab, 0, 0, 0);
    }
    float4 va = *(const float4*)&bias[c*16 + lg*4];
    float4 vb = *(const float4*)&bias[(c+1)*16 + lg*4];
    float a0=aa[0]+va.x, a1=aa[1]+va.y, a2=aa[2]+va.z, a3=aa[3]+va.w;
    float b0=ab[0]+vb.x, b1=ab[1]+vb.y, b2=ab[2]+vb.z, b3=ab[3]+vb.w;
    if (RELU){
      a0=fmaxf(a0,0.f); a1=fmaxf(a1,0.f); a2=fmaxf(a2,0.f); a3=fmaxf(a3,0.f);
      b0=fmaxf(b0,0.f); b1=fmaxf(b1,0.f); b2=fmaxf(b2,0.f); b3=fmaxf(b3,0.f);
    }
    ushort4 pa; pa.x=f2b(a0); pa.y=f2b(a1); pa.z=f2b(a2); pa.w=f2b(a3);
    ushort4 pb; pb.x=f2b(b0); pb.y=f2b(b1); pb.z=f2b(b2); pb.w=f2b(b3);
    *(ushort4*)&patch[pidx(n, c*32 + lg*8)]     = pa;
    *(ushort4*)&patch[pidx(n, (c+1)*32 + lg*8)] = pb;
  }
}

__global__ __launch_bounds__(512, 2) void fused_pc(
    const float* __restrict__ sig, const float* __restrict__ comp,
    const unsigned short* __restrict__ W1t, const unsigned short* __restrict__ W2t,
    const unsigned short* __restrict__ W3t, const unsigned short* __restrict__ W4t,
    const float* __restrict__ c0p, const float* __restrict__ b1p,
    const float* __restrict__ b2p, const float* __restrict__ b3p,
    float* __restrict__ out)
{
  __shared__ unsigned short ring[RING * 4096];   // 64 KiB
  __shared__ int flags[RING];

  const int tid = threadIdx.x;
  const int l   = tid & 63;
  const int w   = tid >> 6;
  if (tid < RING) flags[tid] = 0;
  __syncthreads();                                // only barrier in the kernel

  const long nb = (long)blockIdx.x * 512;

  if (w < NPROD){
    // ================= producer =================
    const float4* __restrict__ sigv  = (const float4*)sig;
    const float4* __restrict__ compv = (const float4*)comp;
    for (int t = w; t < PATCHES; t += NPROD){
      const int s = t & (RING - 1);
      const int want = (t >> 3) * 2;
      while (__hip_atomic_load(&flags[s], __ATOMIC_ACQUIRE, __HIP_MEMORY_SCOPE_WORKGROUP) != want)
        __builtin_amdgcn_s_sleep(1);
      unsigned short* patch = ring + s*4096;
      const long n0 = nb + t*16;

      // sig -> patch cols 0..127
      #pragma unroll 2
      for (int j = 0; j < 8; ++j){
        int slot = l + 64*j;                 // row = slot>>5 (0..15), c4 = slot&31
        int row = slot >> 5, c4 = slot & 31;
        float4 v = sigv[(n0 + row)*32 + c4];
        ushort4 p; p.x=f2b(v.x); p.y=f2b(v.y); p.z=f2b(v.z); p.w=f2b(v.w);
        *(ushort4*)&patch[pidx(row, c4*8)] = p;
      }
      // sum_k comp -> patch cols 128..255
      #pragma unroll 2
      for (int j = 0; j < 8; ++j){
        int slot = l + 64*j;
        int row = slot >> 5, c4 = slot & 31;
        long base = (n0 + row)*32 + c4;
        float4 sv = compv[base];
        #pragma unroll
        for (int k = 1; k < 8; ++k){
          float4 v = compv[(long)k*(NN*32) + base];
          sv.x += v.x; sv.y += v.y; sv.z += v.z; sv.w += v.w;
        }
        ushort4 p; p.x=f2b(sv.x); p.y=f2b(sv.y); p.z=f2b(sv.z); p.w=f2b(sv.w);
        *(ushort4*)&patch[pidx(row, 256 + c4*8)] = p;
      }
      if (l == 0)
        __hip_atomic_store(&flags[s], want + 1, __ATOMIC_RELEASE, __HIP_MEMORY_SCOPE_WORKGROUP);
    }
  } else {
    // ================= consumer =================
    const int cj = w - NPROD;
    const int n  = l & 15, lg = l >> 4;
    for (int t = cj; t < PATCHES; t += NCONS){
      const int s = t & (RING - 1);
      const int want = (t >> 3) * 2 + 1;
      while (__hip_atomic_load(&flags[s], __ATOMIC_ACQUIRE, __HIP_MEMORY_SCOPE_WORKGROUP) != want)
        __builtin_amdgcn_s_sleep(1);
      unsigned short* patch = ring + s*4096;
      const long n0 = nb + t*16;

      layer_p<256, 10, true>(patch, n, lg, W1t, c0p);
      layer_p<160, 10, true>(patch, n, lg, W2t, b1p);
      layer_p<160, 10, true>(patch, n, lg, W3t, b2p);

      // output layer: read act frags, RELEASE the slot, then compute+store
      short8 bf[5];
      #pragma unroll
      for (int ks = 0; ks < 5; ++ks)
        bf[ks] = *(const short8*)&patch[pidx(n, ks*64 + lg*16)];
      if (l == 0)
        __hip_atomic_store(&flags[s], want + 1, __ATOMIC_RELEASE, __HIP_MEMORY_SCOPE_WORKGROUP);

      #pragma unroll
      for (int c = 0; c < 8; c += 2){
        short8 wa[5], wb[5];
        #pragma unroll
        for (int ks = 0; ks < 5; ++ks){
          wa[ks] = *(const short8*)&W4t[(c*16 + n)*160 + ks*32 + lg*8];
          wb[ks] = *(const short8*)&W4t[((c+1)*16 + n)*160 + ks*32 + lg*8];
        }
        f32x4 aa = (f32x4){0.f,0.f,0.f,0.f};
        f32x4 ab = (f32x4){0.f,0.f,0.f,0.f};
        #pragma unroll
        for (int ks = 0; ks < 5; ++ks){
          aa = __builtin_amdgcn_mfma_f32_16x16x32_bf16(wa[ks], bf[ks], aa, 0, 0, 0);
          ab = __builtin_amdgcn_mfma_f32_16x16x32_bf16(wb[ks], bf[ks], ab, 0, 0, 0);
        }
        float4 va = *(const float4*)&b3p[c*16 + lg*4];
        float4 vb = *(const float4*)&b3p[(c+1)*16 + lg*4];
        float4 oa; oa.x=aa[0]+va.x; oa.y=aa[1]+va.y; oa.z=aa[2]+va.z; oa.w=aa[3]+va.w;
        float4 ob; ob.x=ab[0]+vb.x; ob.y=ab[1]+vb.y; ob.z=ab[2]+vb.z; ob.w=ab[3]+vb.w;
        *(float4*)&out[(n0 + n)*128 + c*16 + lg*4]     = oa;
        *(float4*)&out[(n0 + n)*128 + (c+1)*16 + lg*4] = ob;
      }
    }
  }
}

// ---------------- launch ----------------
extern "C" void kernel_launch(void* const* d_in, const int* in_sizes, int n_in,
                              void* d_out, int out_size, void* d_ws, size_t ws_size,
                              hipStream_t stream)
{
  const float* sig  = (const float*)d_in[0];
  const float* comp = (const float*)d_in[1];
  const float* Wm   = (const float*)d_in[2];
  const float* bm   = (const float*)d_in[3];
  const float* Wu   = (const float*)d_in[4];
  const float* bu   = (const float*)d_in[5];
  const float* W0   = (const float*)d_in[6];
  const float* b0   = (const float*)d_in[7];
  const float* W1   = (const float*)d_in[8];
  const float* b1   = (const float*)d_in[9];
  const float* W2   = (const float*)d_in[10];
  const float* b2   = (const float*)d_in[11];
  const float* W3   = (const float*)d_in[12];
  const float* b3   = (const float*)d_in[13];

  char* ws = (char*)d_ws;
  float* Wfold  = (float*)(ws + 0);          // 65536
  float* bias_r = (float*)(ws + 65536);      // 512
  float* c0p    = (float*)(ws + 66048);      // 640
  float* b1p    = (float*)(ws + 66688);      // 640
  float* b2p    = (float*)(ws + 67328);      // 640
  float* b3p    = (float*)(ws + 67968);      // 512
  unsigned short* W1t = (unsigned short*)(ws + 69632);    // 81920
  unsigned short* W2t = (unsigned short*)(ws + 151552);   // 51200
  unsigned short* W3t = (unsigned short*)(ws + 202752);   // 51200
  unsigned short* W4t = (unsigned short*)(ws + 253952);   // 40960

  prep1<<<129, 128, 0, stream>>>(Wm, Wu, bm, bu, Wfold, bias_r);
  prep2<<<443, 256, 0, stream>>>(W0, b0, W1, b1, W2, b2, W3, b3, Wfold, bias_r,
                                 W1t, W2t, W3t, W4t, c0p, b1p, b2p, b3p);
  fused_pc<<<512, 512, 0, stream>>>(sig, comp, W1t, W2t, W3t, W4t,
                                    c0p, b1p, b2p, b3p, (float*)d_out);
}

// Round 8
// 1149.319 us; speedup vs baseline: 1.6362x; 1.6362x over previous
//
#include <hip/hip_runtime.h>

#define NN 262144

typedef __attribute__((ext_vector_type(8))) short short8;
typedef __attribute__((ext_vector_type(4))) float f32x4;

__device__ __forceinline__ unsigned short f2b(float x){
  union { float f; unsigned int u; } c; c.f = x;
  unsigned int u = c.u;
  unsigned int r = (u + 0x7FFFu + ((u >> 16) & 1u)) >> 16;
  return (unsigned short)r;
}

// ---------------- precompute: Wfold = Wm@Wu, bias_r = K*bm@Wu + bu ----------------
__global__ void prep1(const float* __restrict__ Wm, const float* __restrict__ Wu,
                      const float* __restrict__ bm, const float* __restrict__ bu,
                      float* __restrict__ Wfold, float* __restrict__ bias_r)
{
  int j = threadIdx.x;          // 0..127
  int i = blockIdx.x;           // 0..128 (128 => bias row)
  if (i < 128){
    float s = 0.f;
    for (int k = 0; k < 128; ++k) s += Wm[i*128 + k] * Wu[k*128 + j];
    Wfold[i*128 + j] = s;
  } else {
    float s = bu[j];
    for (int m = 0; m < 128; ++m) s += 8.0f * bm[m] * Wu[m*128 + j];
    bias_r[j] = s;
  }
}

// ---------------- precompute: transposed, padded, bf16 weights + folded biases ----
__global__ void prep2(const float* __restrict__ W0, const float* __restrict__ b0,
                      const float* __restrict__ W1, const float* __restrict__ b1,
                      const float* __restrict__ W2, const float* __restrict__ b2,
                      const float* __restrict__ W3, const float* __restrict__ b3,
                      const float* __restrict__ Wfold, const float* __restrict__ bias_r,
                      unsigned short* __restrict__ W1t, unsigned short* __restrict__ W2t,
                      unsigned short* __restrict__ W3t, unsigned short* __restrict__ W4t,
                      float* __restrict__ c0p, float* __restrict__ b1p,
                      float* __restrict__ b2p, float* __restrict__ b3p)
{
  int g = blockIdx.x * 256 + threadIdx.x;
  if (g < 40960){                       // W1t: c = g%160, k = g/160
    int c = g % 160, k = g / 160;
    float v = 0.f;
    if (c < 132){
      if (k < 128) v = W0[k*132 + c];
      else {
        int i = k - 128; float s = 0.f;
        for (int m = 0; m < 128; ++m) s += Wfold[i*128 + m] * W0[(128 + m)*132 + c];
        v = s;
      }
    }
    W1t[c*256 + k] = f2b(v);
  } else if (g < 66560){                // W2t
    int idx = g - 40960; int c = idx % 160, k = idx / 160;
    float v = (c < 132 && k < 132) ? W1[k*132 + c] : 0.f;
    W2t[c*160 + k] = f2b(v);
  } else if (g < 92160){                // W3t
    int idx = g - 66560; int c = idx % 160, k = idx / 160;
    float v = (c < 132 && k < 132) ? W2[k*132 + c] : 0.f;
    W3t[c*160 + k] = f2b(v);
  } else if (g < 112640){               // W4t [128][160]
    int idx = g - 92160; int c = idx & 127, k = idx >> 7;
    float v = (k < 132) ? W3[k*128 + c] : 0.f;
    W4t[c*160 + k] = f2b(v);
  } else if (g < 113248){               // biases
    int idx = g - 112640;
    if (idx < 160){
      int c = idx; float v = 0.f;
      if (c < 132){
        float s = b0[c];
        for (int k = 0; k < 128; ++k) s += bias_r[k] * W0[(128 + k)*132 + c];
        v = s;
      }
      c0p[c] = v;
    } else if (idx < 320){ int c = idx - 160; b1p[c] = (c < 132) ? b1[c] : 0.f; }
    else if (idx < 480){ int c = idx - 320; b2p[c] = (c < 132) ? b2[c] : 0.f; }
    else               { int c = idx - 480; b3p[c] = b3[c]; }
  }
}

// ---------------- role-swapping fused kernel ----------------
// 512 blocks x 512 threads (8 waves), 8 tiles of 64 nodes per block.
// LDS: 2 x 32 KiB ACT buffers; each = 4 patches of [16 rows][256 bf16]
// (row stride 512 B, XOR swizzle byte ^= (row&7)<<4 -- proven R2/R6 layout).
// Phase p: waves grp==(p&1) stage tile p+1 -> buf[(p+1)&1];
//          the other 4 waves each chain ONE private 16-node patch of tile p
//          (R6-proven in-place 4-layer MFMA chain, no intra-chain sync).
// One __syncthreads per phase. No spin flags. No VGPR cap (512,2 -> 256).

__device__ __forceinline__ int pidx(int row, int colByte){
  return (row*512 + (colByte ^ ((row & 7) << 4))) >> 1;   // ushort index, row 0..15
}

template<int NV>
__device__ __forceinline__ void stage(unsigned short* __restrict__ buf, long nodeBase,
                                      int vt, const float4* __restrict__ sigv,
                                      const float4* __restrict__ compv)
{
  constexpr int J = 2048 / NV;        // float4 positions per thread
  // sig -> cols 0..127
  #pragma unroll
  for (int j = 0; j < J; ++j){
    int slot = vt + NV*j;             // 0..2047: row = slot>>5 (0..63), c4 = slot&31
    int row = slot >> 5, c4 = slot & 31;
    float4 v = sigv[nodeBase*32 + slot];
    ushort4 p; p.x=f2b(v.x); p.y=f2b(v.y); p.z=f2b(v.z); p.w=f2b(v.w);
    *(ushort4*)&buf[(row>>4)*4096 + pidx(row & 15, c4*8)] = p;
  }
  // sum_k comp -> cols 128..255
  float4 sum[J];
  #pragma unroll
  for (int j = 0; j < J; ++j) sum[j] = compv[nodeBase*32 + vt + NV*j];
  #pragma unroll
  for (int k = 1; k < 8; ++k){
    #pragma unroll
    for (int j = 0; j < J; ++j){
      float4 v = compv[(long)k*(NN*32) + nodeBase*32 + vt + NV*j];
      sum[j].x += v.x; sum[j].y += v.y; sum[j].z += v.z; sum[j].w += v.w;
    }
  }
  #pragma unroll
  for (int j = 0; j < J; ++j){
    int slot = vt + NV*j;
    int row = slot >> 5, c4 = slot & 31;
    ushort4 p; p.x=f2b(sum[j].x); p.y=f2b(sum[j].y); p.z=f2b(sum[j].z); p.w=f2b(sum[j].w);
    *(ushort4*)&buf[(row>>4)*4096 + pidx(row & 15, 256 + c4*8)] = p;
  }
}

template<int KD, int NT, bool RELU>
__device__ __forceinline__ void layer_p(unsigned short* __restrict__ patch,
                                        int n, int lg,
                                        const unsigned short* __restrict__ Wt,
                                        const float* __restrict__ bias)
{
  constexpr int KS = KD / 32;
  short8 bf[KS];
  #pragma unroll
  for (int ks = 0; ks < KS; ++ks)
    bf[ks] = *(const short8*)&patch[pidx(n, ks*64 + lg*16)];

  #pragma unroll
  for (int c = 0; c < NT; c += 2){
    short8 wa[KS], wb[KS];
    #pragma unroll
    for (int ks = 0; ks < KS; ++ks){
      wa[ks] = *(const short8*)&Wt[(c*16 + n)*KD + ks*32 + lg*8];
      wb[ks] = *(const short8*)&Wt[((c+1)*16 + n)*KD + ks*32 + lg*8];
    }
    f32x4 aa = (f32x4){0.f,0.f,0.f,0.f};
    f32x4 ab = (f32x4){0.f,0.f,0.f,0.f};
    #pragma unroll
    for (int ks = 0; ks < KS; ++ks){
      aa = __builtin_amdgcn_mfma_f32_16x16x32_bf16(wa[ks], bf[ks], aa, 0, 0, 0);
      ab = __builtin_amdgcn_mfma_f32_16x16x32_bf16(wb[ks], bf[ks], ab, 0, 0, 0);
    }
    float4 va = *(const float4*)&bias[c*16 + lg*4];
    float4 vb = *(const float4*)&bias[(c+1)*16 + lg*4];
    float a0=aa[0]+va.x, a1=aa[1]+va.y, a2=aa[2]+va.z, a3=aa[3]+va.w;
    float b0=ab[0]+vb.x, b1=ab[1]+vb.y, b2=ab[2]+vb.z, b3=ab[3]+vb.w;
    if (RELU){
      a0=fmaxf(a0,0.f); a1=fmaxf(a1,0.f); a2=fmaxf(a2,0.f); a3=fmaxf(a3,0.f);
      b0=fmaxf(b0,0.f); b1=fmaxf(b1,0.f); b2=fmaxf(b2,0.f); b3=fmaxf(b3,0.f);
    }
    ushort4 pa; pa.x=f2b(a0); pa.y=f2b(a1); pa.z=f2b(a2); pa.w=f2b(a3);
    ushort4 pb; pb.x=f2b(b0); pb.y=f2b(b1); pb.z=f2b(b2); pb.w=f2b(b3);
    *(ushort4*)&patch[pidx(n, c*32 + lg*8)]     = pa;
    *(ushort4*)&patch[pidx(n, (c+1)*32 + lg*8)] = pb;
  }
}

__device__ __forceinline__ void chain16(unsigned short* __restrict__ patch,
                                        int n, int lg, long n0,
                                        const unsigned short* __restrict__ W1t,
                                        const unsigned short* __restrict__ W2t,
                                        const unsigned short* __restrict__ W3t,
                                        const unsigned short* __restrict__ W4t,
                                        const float* __restrict__ c0p,
                                        const float* __restrict__ b1p,
                                        const float* __restrict__ b2p,
                                        const float* __restrict__ b3p,
                                        float* __restrict__ out)
{
  layer_p<256, 10, true>(patch, n, lg, W1t, c0p);
  layer_p<160, 10, true>(patch, n, lg, W2t, b1p);
  layer_p<160, 10, true>(patch, n, lg, W3t, b2p);

  short8 bf[5];
  #pragma unroll
  for (int ks = 0; ks < 5; ++ks)
    bf[ks] = *(const short8*)&patch[pidx(n, ks*64 + lg*16)];
  #pragma unroll
  for (int c = 0; c < 8; c += 2){
    short8 wa[5], wb[5];
    #pragma unroll
    for (int ks = 0; ks < 5; ++ks){
      wa[ks] = *(const short8*)&W4t[(c*16 + n)*160 + ks*32 + lg*8];
      wb[ks] = *(const short8*)&W4t[((c+1)*16 + n)*160 + ks*32 + lg*8];
    }
    f32x4 aa = (f32x4){0.f,0.f,0.f,0.f};
    f32x4 ab = (f32x4){0.f,0.f,0.f,0.f};
    #pragma unroll
    for (int ks = 0; ks < 5; ++ks){
      aa = __builtin_amdgcn_mfma_f32_16x16x32_bf16(wa[ks], bf[ks], aa, 0, 0, 0);
      ab = __builtin_amdgcn_mfma_f32_16x16x32_bf16(wb[ks], bf[ks], ab, 0, 0, 0);
    }
    float4 va = *(const float4*)&b3p[c*16 + lg*4];
    float4 vb = *(const float4*)&b3p[(c+1)*16 + lg*4];
    float4 oa; oa.x=aa[0]+va.x; oa.y=aa[1]+va.y; oa.z=aa[2]+va.z; oa.w=aa[3]+va.w;
    float4 ob; ob.x=ab[0]+vb.x; ob.y=ab[1]+vb.y; ob.z=ab[2]+vb.z; ob.w=ab[3]+vb.w;
    *(float4*)&out[(n0 + n)*128 + c*16 + lg*4]     = oa;
    *(float4*)&out[(n0 + n)*128 + (c+1)*16 + lg*4] = ob;
  }
}

#define TPB 8   // tiles (of 64 nodes) per block

__global__ __launch_bounds__(512, 2) void fused_swap(
    const float* __restrict__ sig, const float* __restrict__ comp,
    const unsigned short* __restrict__ W1t, const unsigned short* __restrict__ W2t,
    const unsigned short* __restrict__ W3t, const unsigned short* __restrict__ W4t,
    const float* __restrict__ c0p, const float* __restrict__ b1p,
    const float* __restrict__ b2p, const float* __restrict__ b3p,
    float* __restrict__ out)
{
  __shared__ unsigned short bufs[2][16384];   // 2 x 32 KiB

  const int tid = threadIdx.x;
  const int l   = tid & 63;
  const int w   = tid >> 6;        // 0..7
  const int grp = w >> 2;          // 0 or 1
  const int cw  = w & 3;           // wave within group
  const long tile0 = (long)blockIdx.x * TPB;

  const float4* __restrict__ sigv  = (const float4*)sig;
  const float4* __restrict__ compv = (const float4*)comp;

  // prologue: all 8 waves stage tile 0 into bufs[0]
  stage<512>(bufs[0], tile0*64, tid, sigv, compv);

  for (int p = 0; p < TPB; ++p){
    __syncthreads();
    if (grp == (p & 1)){
      if (p + 1 < TPB)
        stage<256>(bufs[(p+1)&1], (tile0 + p + 1)*64, cw*64 + l, sigv, compv);
    } else {
      unsigned short* patch = bufs[p&1] + cw*4096;
      const long n0 = (tile0 + p)*64 + cw*16;
      chain16(patch, l & 15, l >> 4, n0, W1t, W2t, W3t, W4t, c0p, b1p, b2p, b3p, out);
    }
  }
}

// ---------------- launch ----------------
extern "C" void kernel_launch(void* const* d_in, const int* in_sizes, int n_in,
                              void* d_out, int out_size, void* d_ws, size_t ws_size,
                              hipStream_t stream)
{
  const float* sig  = (const float*)d_in[0];
  const float* comp = (const float*)d_in[1];
  const float* Wm   = (const float*)d_in[2];
  const float* bm   = (const float*)d_in[3];
  const float* Wu   = (const float*)d_in[4];
  const float* bu   = (const float*)d_in[5];
  const float* W0   = (const float*)d_in[6];
  const float* b0   = (const float*)d_in[7];
  const float* W1   = (const float*)d_in[8];
  const float* b1   = (const float*)d_in[9];
  const float* W2   = (const float*)d_in[10];
  const float* b2   = (const float*)d_in[11];
  const float* W3   = (const float*)d_in[12];
  const float* b3   = (const float*)d_in[13];

  char* ws = (char*)d_ws;
  float* Wfold  = (float*)(ws + 0);          // 65536
  float* bias_r = (float*)(ws + 65536);      // 512
  float* c0p    = (float*)(ws + 66048);      // 640
  float* b1p    = (float*)(ws + 66688);      // 640
  float* b2p    = (float*)(ws + 67328);      // 640
  float* b3p    = (float*)(ws + 67968);      // 512
  unsigned short* W1t = (unsigned short*)(ws + 69632);    // 81920
  unsigned short* W2t = (unsigned short*)(ws + 151552);   // 51200
  unsigned short* W3t = (unsigned short*)(ws + 202752);   // 51200
  unsigned short* W4t = (unsigned short*)(ws + 253952);   // 40960

  prep1<<<129, 128, 0, stream>>>(Wm, Wu, bm, bu, Wfold, bias_r);
  prep2<<<443, 256, 0, stream>>>(W0, b0, W1, b1, W2, b2, W3, b3, Wfold, bias_r,
                                 W1t, W2t, W3t, W4t, c0p, b1p, b2p, b3p);
  fused_swap<<<512, 512, 0, stream>>>(sig, comp, W1t, W2t, W3t, W4t,
                                      c0p, b1p, b2p, b3p, (float*)d_out);
}

// Round 9
// 562.836 us; speedup vs baseline: 3.3411x; 2.0420x over previous
//
#include <hip/hip_runtime.h>

#define NN 262144

typedef __attribute__((ext_vector_type(8))) short short8;
typedef __attribute__((ext_vector_type(4))) float f32x4;

__device__ __forceinline__ unsigned short f2b(float x){
  union { float f; unsigned int u; } c; c.f = x;
  unsigned int u = c.u;
  unsigned int r = (u + 0x7FFFu + ((u >> 16) & 1u)) >> 16;
  return (unsigned short)r;
}

// ---------------- precompute: Wfold = Wm@Wu, bias_r = K*bm@Wu + bu ----------------
__global__ void prep1(const float* __restrict__ Wm, const float* __restrict__ Wu,
                      const float* __restrict__ bm, const float* __restrict__ bu,
                      float* __restrict__ Wfold, float* __restrict__ bias_r)
{
  int j = threadIdx.x;          // 0..127
  int i = blockIdx.x;           // 0..128 (128 => bias row)
  if (i < 128){
    float s = 0.f;
    for (int k = 0; k < 128; ++k) s += Wm[i*128 + k] * Wu[k*128 + j];
    Wfold[i*128 + j] = s;
  } else {
    float s = bu[j];
    for (int m = 0; m < 128; ++m) s += 8.0f * bm[m] * Wu[m*128 + j];
    bias_r[j] = s;
  }
}

// ---------------- precompute: transposed, padded, bf16 weights + folded biases ----
__global__ void prep2(const float* __restrict__ W0, const float* __restrict__ b0,
                      const float* __restrict__ W1, const float* __restrict__ b1,
                      const float* __restrict__ W2, const float* __restrict__ b2,
                      const float* __restrict__ W3, const float* __restrict__ b3,
                      const float* __restrict__ Wfold, const float* __restrict__ bias_r,
                      unsigned short* __restrict__ W1t, unsigned short* __restrict__ W2t,
                      unsigned short* __restrict__ W3t, unsigned short* __restrict__ W4t,
                      float* __restrict__ c0p, float* __restrict__ b1p,
                      float* __restrict__ b2p, float* __restrict__ b3p)
{
  int g = blockIdx.x * 256 + threadIdx.x;
  if (g < 40960){                       // W1t: c = g%160, k = g/160
    int c = g % 160, k = g / 160;
    float v = 0.f;
    if (c < 132){
      if (k < 128) v = W0[k*132 + c];
      else {
        int i = k - 128; float s = 0.f;
        for (int m = 0; m < 128; ++m) s += Wfold[i*128 + m] * W0[(128 + m)*132 + c];
        v = s;
      }
    }
    W1t[c*256 + k] = f2b(v);
  } else if (g < 66560){                // W2t
    int idx = g - 40960; int c = idx % 160, k = idx / 160;
    float v = (c < 132 && k < 132) ? W1[k*132 + c] : 0.f;
    W2t[c*160 + k] = f2b(v);
  } else if (g < 92160){                // W3t
    int idx = g - 66560; int c = idx % 160, k = idx / 160;
    float v = (c < 132 && k < 132) ? W2[k*132 + c] : 0.f;
    W3t[c*160 + k] = f2b(v);
  } else if (g < 112640){               // W4t [128][160]
    int idx = g - 92160; int c = idx & 127, k = idx >> 7;
    float v = (k < 132) ? W3[k*128 + c] : 0.f;
    W4t[c*160 + k] = f2b(v);
  } else if (g < 113248){               // biases
    int idx = g - 112640;
    if (idx < 160){
      int c = idx; float v = 0.f;
      if (c < 132){
        float s = b0[c];
        for (int k = 0; k < 128; ++k) s += bias_r[k] * W0[(128 + k)*132 + c];
        v = s;
      }
      c0p[c] = v;
    } else if (idx < 320){ int c = idx - 160; b1p[c] = (c < 132) ? b1[c] : 0.f; }
    else if (idx < 480){ int c = idx - 320; b2p[c] = (c < 132) ? b2[c] : 0.f; }
    else               { int c = idx - 480; b3p[c] = b3[c]; }
  }
}

// ---------------- Kernel S: pure streaming component sum -> bf16 (proven 181 us) ----
__global__ __launch_bounds__(256) void sum_comp(const float4* __restrict__ comp,
                                                ushort4* __restrict__ summed)
{
  long base = (long)blockIdx.x * 256 + threadIdx.x;
  #pragma unroll 4
  for (int it = 0; it < 16; ++it){
    long f = base + (long)it * 524288;
    float4 s = comp[f];
    #pragma unroll
    for (int k = 1; k < 8; ++k){
      float4 v = comp[f + (long)k * (NN*32)];
      s.x += v.x; s.y += v.y; s.z += v.z; s.w += v.w;
    }
    ushort4 p; p.x=f2b(s.x); p.y=f2b(s.y); p.z=f2b(s.z); p.w=f2b(s.w);
    summed[f] = p;
  }
}

// ---------------- Kernel G: MLP, 32-node tiles, padded-stride LDS (no swizzle) ----
// LDS: ACT [32][264 ushorts] (stride 528 B == 132 dw == 4 mod 32 banks ->
//      b128 reads: bank group (r + 4ks + lg) mod 8, 2 lanes/group = free);
//      H [32][168 ushorts] (stride 336 B: group (5r+4ks+lg) mod 8 = free).
// 27.6 KiB -> 5 blocks/CU.  4 waves: wave = (ngroup = w&1) x (fs = w>>1).
// Per layer each wave computes 5 (or 4) ct-tiles sequentially (unroll 1 keeps
// VGPR ~85 < 128 cap of __launch_bounds__(256,4): no spill).
// Swapped-operand MFMA (proven): D[feat][node]; node = ng*16 + (l&15).

#define ACT_ST 264
#define H_ST   168

template<int KD, int SST, int DST, int NCT, bool RELU>
__device__ __forceinline__ void layerV(const unsigned short* __restrict__ smem, int rb,
                                       unsigned short* __restrict__ smw, int wb,
                                       int r, int lr, int lg, int fs,
                                       const unsigned short* __restrict__ Wt,
                                       const float* __restrict__ bias)
{
  constexpr int KS = KD / 32;
  short8 bf[KS];
  #pragma unroll
  for (int ks = 0; ks < KS; ++ks)
    bf[ks] = *(const short8*)&smem[rb + r*SST + ks*32 + lg*8];

  #pragma unroll 1
  for (int i = 0; i < NCT; ++i){
    const int ct = fs + 2*i;
    short8 wf[KS];
    #pragma unroll
    for (int ks = 0; ks < KS; ++ks)
      wf[ks] = *(const short8*)&Wt[(ct*16 + lr)*KD + ks*32 + lg*8];
    f32x4 acc = (f32x4){0.f,0.f,0.f,0.f};
    #pragma unroll
    for (int ks = 0; ks < KS; ++ks)
      acc = __builtin_amdgcn_mfma_f32_16x16x32_bf16(wf[ks], bf[ks], acc, 0, 0, 0);
    float4 bv = *(const float4*)&bias[ct*16 + lg*4];
    float v0 = acc[0]+bv.x, v1 = acc[1]+bv.y, v2 = acc[2]+bv.z, v3 = acc[3]+bv.w;
    if (RELU){ v0=fmaxf(v0,0.f); v1=fmaxf(v1,0.f); v2=fmaxf(v2,0.f); v3=fmaxf(v3,0.f); }
    ushort4 p; p.x=f2b(v0); p.y=f2b(v1); p.z=f2b(v2); p.w=f2b(v3);
    *(ushort4*)&smw[wb + r*DST + ct*16 + lg*4] = p;
  }
}

__global__ __launch_bounds__(256, 4) void mlp32(
    const float* __restrict__ sig, const unsigned short* __restrict__ summed,
    const unsigned short* __restrict__ W1t, const unsigned short* __restrict__ W2t,
    const unsigned short* __restrict__ W3t, const unsigned short* __restrict__ W4t,
    const float* __restrict__ c0p, const float* __restrict__ b1p,
    const float* __restrict__ b2p, const float* __restrict__ b3p,
    float* __restrict__ out)
{
  __shared__ unsigned short smem[32*ACT_ST + 32*H_ST];   // 27648 B
  const int ACT = 0, H1 = 32*ACT_ST;

  const int t  = threadIdx.x;
  const int l  = t & 63;
  const int wv = t >> 6;
  const int lr = l & 15, lg = l >> 4;
  const int ng = wv & 1, fs = wv >> 1;
  const int r  = ng*16 + lr;
  const long n0 = (long)blockIdx.x * 32;

  // ---- stage: sig (f32 -> bf16) into ACT cols 0..127 ----
  const float4* __restrict__ sigv = (const float4*)sig;
  #pragma unroll
  for (int j = 0; j < 4; ++j){
    int slot = t + 256*j;                   // 0..1023: row = slot>>5, c4 = slot&31
    int row = slot >> 5, c4 = slot & 31;
    float4 v = sigv[(n0 + row)*32 + c4];
    ushort4 p; p.x=f2b(v.x); p.y=f2b(v.y); p.z=f2b(v.z); p.w=f2b(v.w);
    *(ushort4*)&smem[ACT + row*ACT_ST + c4*4] = p;
  }
  // ---- stage: summed (bf16) into ACT cols 128..255 ----
  #pragma unroll
  for (int j = 0; j < 2; ++j){
    int slot = t + 256*j;                   // 0..511: row = slot>>4, c8 = slot&15
    int row = slot >> 4, c8 = slot & 15;
    short8 v = *(const short8*)&summed[(n0 + row)*128 + c8*8];
    *(short8*)&smem[ACT + row*ACT_ST + 128 + c8*8] = v;
  }
  __syncthreads();

  layerV<256, ACT_ST, H_ST,   5, true>(smem, ACT, smem, H1,  r, lr, lg, fs, W1t, c0p);
  __syncthreads();
  layerV<160, H_ST,   ACT_ST, 5, true>(smem, H1,  smem, ACT, r, lr, lg, fs, W2t, b1p);
  __syncthreads();
  layerV<160, ACT_ST, H_ST,   5, true>(smem, ACT, smem, H1,  r, lr, lg, fs, W3t, b2p);
  __syncthreads();

  // ---- output layer: KD=160, 8 ct tiles total, 4 per wave, float4 -> global ----
  {
    short8 bf[5];
    #pragma unroll
    for (int ks = 0; ks < 5; ++ks)
      bf[ks] = *(const short8*)&smem[H1 + r*H_ST + ks*32 + lg*8];
    #pragma unroll 1
    for (int i = 0; i < 4; ++i){
      const int ct = fs + 2*i;
      short8 wf[5];
      #pragma unroll
      for (int ks = 0; ks < 5; ++ks)
        wf[ks] = *(const short8*)&W4t[(ct*16 + lr)*160 + ks*32 + lg*8];
      f32x4 acc = (f32x4){0.f,0.f,0.f,0.f};
      #pragma unroll
      for (int ks = 0; ks < 5; ++ks)
        acc = __builtin_amdgcn_mfma_f32_16x16x32_bf16(wf[ks], bf[ks], acc, 0, 0, 0);
      float4 bv = *(const float4*)&b3p[ct*16 + lg*4];
      float4 o; o.x=acc[0]+bv.x; o.y=acc[1]+bv.y; o.z=acc[2]+bv.z; o.w=acc[3]+bv.w;
      *(float4*)&out[(n0 + r)*128 + ct*16 + lg*4] = o;
    }
  }
}

// ---------------- launch ----------------
extern "C" void kernel_launch(void* const* d_in, const int* in_sizes, int n_in,
                              void* d_out, int out_size, void* d_ws, size_t ws_size,
                              hipStream_t stream)
{
  const float* sig  = (const float*)d_in[0];
  const float* comp = (const float*)d_in[1];
  const float* Wm   = (const float*)d_in[2];
  const float* bm   = (const float*)d_in[3];
  const float* Wu   = (const float*)d_in[4];
  const float* bu   = (const float*)d_in[5];
  const float* W0   = (const float*)d_in[6];
  const float* b0   = (const float*)d_in[7];
  const float* W1   = (const float*)d_in[8];
  const float* b1   = (const float*)d_in[9];
  const float* W2   = (const float*)d_in[10];
  const float* b2   = (const float*)d_in[11];
  const float* W3   = (const float*)d_in[12];
  const float* b3   = (const float*)d_in[13];

  char* ws = (char*)d_ws;
  float* Wfold  = (float*)(ws + 0);          // 65536
  float* bias_r = (float*)(ws + 65536);      // 512
  float* c0p    = (float*)(ws + 66048);      // 640
  float* b1p    = (float*)(ws + 66688);      // 640
  float* b2p    = (float*)(ws + 67328);      // 640
  float* b3p    = (float*)(ws + 67968);      // 512
  unsigned short* W1t = (unsigned short*)(ws + 69632);    // 81920
  unsigned short* W2t = (unsigned short*)(ws + 151552);   // 51200
  unsigned short* W3t = (unsigned short*)(ws + 202752);   // 51200
  unsigned short* W4t = (unsigned short*)(ws + 253952);   // 40960
  unsigned short* summed = (unsigned short*)(ws + (1 << 20));   // 67.1 MB @ 1 MB offset

  prep1<<<129, 128, 0, stream>>>(Wm, Wu, bm, bu, Wfold, bias_r);
  prep2<<<443, 256, 0, stream>>>(W0, b0, W1, b1, W2, b2, W3, b3, Wfold, bias_r,
                                 W1t, W2t, W3t, W4t, c0p, b1p, b2p, b3p);
  sum_comp<<<2048, 256, 0, stream>>>((const float4*)comp, (ushort4*)summed);
  mlp32<<<8192, 256, 0, stream>>>(sig, summed, W1t, W2t, W3t, W4t,
                                  c0p, b1p, b2p, b3p, (float*)d_out);
}

// Round 10
// 428.113 us; speedup vs baseline: 4.3925x; 1.3147x over previous
//
#include <hip/hip_runtime.h>

#define NN 262144

typedef __attribute__((ext_vector_type(8))) short short8;
typedef __attribute__((ext_vector_type(4))) float f32x4;

__device__ __forceinline__ unsigned short f2b(float x){
  union { float f; unsigned int u; } c; c.f = x;
  unsigned int u = c.u;
  unsigned int r = (u + 0x7FFFu + ((u >> 16) & 1u)) >> 16;
  return (unsigned short)r;
}

__device__ __forceinline__ short8 pk8(float4 a, float4 b){
  short8 r;
  r[0]=(short)f2b(a.x); r[1]=(short)f2b(a.y); r[2]=(short)f2b(a.z); r[3]=(short)f2b(a.w);
  r[4]=(short)f2b(b.x); r[5]=(short)f2b(b.y); r[6]=(short)f2b(b.z); r[7]=(short)f2b(b.w);
  return r;
}

// ---------------- precompute: Wfold = Wm@Wu, bias_r = K*bm@Wu + bu ----------------
__global__ void prep1(const float* __restrict__ Wm, const float* __restrict__ Wu,
                      const float* __restrict__ bm, const float* __restrict__ bu,
                      float* __restrict__ Wfold, float* __restrict__ bias_r)
{
  int j = threadIdx.x;
  int i = blockIdx.x;
  if (i < 128){
    float s = 0.f;
    for (int k = 0; k < 128; ++k) s += Wm[i*128 + k] * Wu[k*128 + j];
    Wfold[i*128 + j] = s;
  } else {
    float s = bu[j];
    for (int m = 0; m < 128; ++m) s += 8.0f * bm[m] * Wu[m*128 + j];
    bias_r[j] = s;
  }
}

// ---------------- precompute: transposed, padded, bf16 weights + folded biases ----
__global__ void prep2(const float* __restrict__ W0, const float* __restrict__ b0,
                      const float* __restrict__ W1, const float* __restrict__ b1,
                      const float* __restrict__ W2, const float* __restrict__ b2,
                      const float* __restrict__ W3, const float* __restrict__ b3,
                      const float* __restrict__ Wfold, const float* __restrict__ bias_r,
                      unsigned short* __restrict__ W1t, unsigned short* __restrict__ W2t,
                      unsigned short* __restrict__ W3t, unsigned short* __restrict__ W4t,
                      float* __restrict__ c0p, float* __restrict__ b1p,
                      float* __restrict__ b2p, float* __restrict__ b3p)
{
  int g = blockIdx.x * 256 + threadIdx.x;
  if (g < 40960){                       // W1t [160][256]
    int c = g % 160, k = g / 160;
    float v = 0.f;
    if (c < 132){
      if (k < 128) v = W0[k*132 + c];
      else {
        int i = k - 128; float s = 0.f;
        for (int m = 0; m < 128; ++m) s += Wfold[i*128 + m] * W0[(128 + m)*132 + c];
        v = s;
      }
    }
    W1t[c*256 + k] = f2b(v);
  } else if (g < 66560){                // W2t [160][160]
    int idx = g - 40960; int c = idx % 160, k = idx / 160;
    float v = (c < 132 && k < 132) ? W1[k*132 + c] : 0.f;
    W2t[c*160 + k] = f2b(v);
  } else if (g < 92160){                // W3t [160][160]
    int idx = g - 66560; int c = idx % 160, k = idx / 160;
    float v = (c < 132 && k < 132) ? W2[k*132 + c] : 0.f;
    W3t[c*160 + k] = f2b(v);
  } else if (g < 112640){               // W4t [128][160]
    int idx = g - 92160; int c = idx & 127, k = idx >> 7;
    float v = (k < 132) ? W3[k*128 + c] : 0.f;
    W4t[c*160 + k] = f2b(v);
  } else if (g < 113248){               // biases
    int idx = g - 112640;
    if (idx < 160){
      int c = idx; float v = 0.f;
      if (c < 132){
        float s = b0[c];
        for (int k = 0; k < 128; ++k) s += bias_r[k] * W0[(128 + k)*132 + c];
        v = s;
      }
      c0p[c] = v;
    } else if (idx < 320){ int c = idx - 160; b1p[c] = (c < 132) ? b1[c] : 0.f; }
    else if (idx < 480){ int c = idx - 320; b2p[c] = (c < 132) ? b2[c] : 0.f; }
    else               { int c = idx - 480; b3p[c] = b3[c]; }
  }
}

// ============== P12: L1+L2, weights in LDS, activations in registers ==============
// 512 blocks x 256 threads (4 waves). LDS: W1L [160][264] (84480 B) + W2L [160][168]
// (53760 B) + 4 per-wave patches [16][168] (21504 B) = 159744 B -> 1 block/CU.
// Chunk = 16 nodes, owned by one wave. No barriers in chunk loop.
// Swapped MFMA (proven): D[feat][node]; lane(lr,lg): node=lr, feats=ct*16+lg*4+r.
// Padded strides: 264 u (528B, dw%32=4) and 168 u (336B, dw%32=20) -> <=2-way banks.

__global__ __launch_bounds__(256) void pass12(
    const float* __restrict__ sig, const float* __restrict__ comp,
    const unsigned short* __restrict__ W1t, const unsigned short* __restrict__ W2t,
    const float* __restrict__ c0p, const float* __restrict__ b1p,
    unsigned short* __restrict__ h2)
{
  __shared__ unsigned short smem[79872];
  const int W1B = 0, W2B = 42240, PB = 69120;

  const int t = threadIdx.x, l = t & 63, wv = t >> 6;
  const int lr = l & 15, lg = l >> 4;

  for (int j = t; j < 5120; j += 256){            // stage W1L (stride 264)
    int c = j >> 5, k8 = j & 31;
    *(short8*)&smem[W1B + c*264 + k8*8] = *(const short8*)&W1t[c*256 + k8*8];
  }
  for (int j = t; j < 3200; j += 256){            // stage W2L (stride 168)
    int c = j / 20, k8 = j % 20;
    *(short8*)&smem[W2B + c*168 + k8*8] = *(const short8*)&W2t[c*160 + k8*8];
  }
  __syncthreads();

  unsigned short* patch = smem + PB + wv*2688;    // [16][168]

  for (int it = 0; it < 8; ++it){
    const long chunk = ((long)blockIdx.x*4 + wv)*8 + it;
    const long n0 = chunk*16;
    const long row = (n0 + lr)*128;               // f32 row base

    // ---- B-frags: sig (k 0..127) + on-the-fly comp sum (k 128..255) ----
    short8 b[8];
    #pragma unroll
    for (int ks = 0; ks < 4; ++ks){
      float4 a0 = *(const float4*)&sig[row + ks*32 + lg*8];
      float4 a1 = *(const float4*)&sig[row + ks*32 + lg*8 + 4];
      b[ks] = pk8(a0, a1);
    }
    #pragma unroll
    for (int ks = 0; ks < 4; ++ks){
      const long d = row + ks*32 + lg*8;
      float4 s0 = *(const float4*)&comp[d];
      float4 s1 = *(const float4*)&comp[d + 4];
      #pragma unroll
      for (int c = 1; c < 8; ++c){
        float4 v0 = *(const float4*)&comp[(long)c*(NN*128) + d];
        float4 v1 = *(const float4*)&comp[(long)c*(NN*128) + d + 4];
        s0.x += v0.x; s0.y += v0.y; s0.z += v0.z; s0.w += v0.w;
        s1.x += v1.x; s1.y += v1.y; s1.z += v1.z; s1.w += v1.w;
      }
      b[4+ks] = pk8(s0, s1);
    }

    // ---- L1: K=256, 10 ct tiles (2-way unrolled), -> patch ----
    #pragma unroll
    for (int c = 0; c < 10; c += 2){
      short8 wa[8], wb[8];
      #pragma unroll
      for (int ks = 0; ks < 8; ++ks){
        wa[ks] = *(const short8*)&smem[W1B + (c*16 + lr)*264 + ks*32 + lg*8];
        wb[ks] = *(const short8*)&smem[W1B + ((c+1)*16 + lr)*264 + ks*32 + lg*8];
      }
      f32x4 aa = (f32x4){0.f,0.f,0.f,0.f};
      f32x4 ab = (f32x4){0.f,0.f,0.f,0.f};
      #pragma unroll
      for (int ks = 0; ks < 8; ++ks){
        aa = __builtin_amdgcn_mfma_f32_16x16x32_bf16(wa[ks], b[ks], aa, 0, 0, 0);
        ab = __builtin_amdgcn_mfma_f32_16x16x32_bf16(wb[ks], b[ks], ab, 0, 0, 0);
      }
      float4 va = *(const float4*)&c0p[c*16 + lg*4];
      float4 vb = *(const float4*)&c0p[(c+1)*16 + lg*4];
      float a0=fmaxf(aa[0]+va.x,0.f), a1=fmaxf(aa[1]+va.y,0.f),
            a2=fmaxf(aa[2]+va.z,0.f), a3=fmaxf(aa[3]+va.w,0.f);
      float b0=fmaxf(ab[0]+vb.x,0.f), b1=fmaxf(ab[1]+vb.y,0.f),
            b2=fmaxf(ab[2]+vb.z,0.f), b3=fmaxf(ab[3]+vb.w,0.f);
      ushort4 pa; pa.x=f2b(a0); pa.y=f2b(a1); pa.z=f2b(a2); pa.w=f2b(a3);
      ushort4 pb; pb.x=f2b(b0); pb.y=f2b(b1); pb.z=f2b(b2); pb.w=f2b(b3);
      *(ushort4*)&patch[lr*168 + c*16 + lg*4]     = pa;
      *(ushort4*)&patch[lr*168 + (c+1)*16 + lg*4] = pb;
    }

    // ---- L2: K=160, B from patch, -> h2 global (bf16) ----
    short8 p2[5];
    #pragma unroll
    for (int ks = 0; ks < 5; ++ks)
      p2[ks] = *(const short8*)&patch[lr*168 + ks*32 + lg*8];
    #pragma unroll
    for (int c = 0; c < 10; c += 2){
      short8 wa[5], wb[5];
      #pragma unroll
      for (int ks = 0; ks < 5; ++ks){
        wa[ks] = *(const short8*)&smem[W2B + (c*16 + lr)*168 + ks*32 + lg*8];
        wb[ks] = *(const short8*)&smem[W2B + ((c+1)*16 + lr)*168 + ks*32 + lg*8];
      }
      f32x4 aa = (f32x4){0.f,0.f,0.f,0.f};
      f32x4 ab = (f32x4){0.f,0.f,0.f,0.f};
      #pragma unroll
      for (int ks = 0; ks < 5; ++ks){
        aa = __builtin_amdgcn_mfma_f32_16x16x32_bf16(wa[ks], p2[ks], aa, 0, 0, 0);
        ab = __builtin_amdgcn_mfma_f32_16x16x32_bf16(wb[ks], p2[ks], ab, 0, 0, 0);
      }
      float4 va = *(const float4*)&b1p[c*16 + lg*4];
      float4 vb = *(const float4*)&b1p[(c+1)*16 + lg*4];
      float a0=fmaxf(aa[0]+va.x,0.f), a1=fmaxf(aa[1]+va.y,0.f),
            a2=fmaxf(aa[2]+va.z,0.f), a3=fmaxf(aa[3]+va.w,0.f);
      float b0=fmaxf(ab[0]+vb.x,0.f), b1v=fmaxf(ab[1]+vb.y,0.f),
            b2=fmaxf(ab[2]+vb.z,0.f), b3=fmaxf(ab[3]+vb.w,0.f);
      ushort4 pa; pa.x=f2b(a0); pa.y=f2b(a1); pa.z=f2b(a2); pa.w=f2b(a3);
      ushort4 pb; pb.x=f2b(b0); pb.y=f2b(b1v); pb.z=f2b(b2); pb.w=f2b(b3);
      *(ushort4*)&h2[(n0 + lr)*160 + c*16 + lg*4]     = pa;
      *(ushort4*)&h2[(n0 + lr)*160 + (c+1)*16 + lg*4] = pb;
    }
  }
}

// ============== P34: L3+L4, weights in LDS, activations in registers ==============
// 512 blocks x 512 threads (8 waves). LDS: W3L [160][168] + W4L [128][168] +
// 8 patches [16][168] = 139776 B -> 1 block/CU.
__global__ __launch_bounds__(512) void pass34(
    const unsigned short* __restrict__ h2,
    const unsigned short* __restrict__ W3t, const unsigned short* __restrict__ W4t,
    const float* __restrict__ b2p, const float* __restrict__ b3p,
    float* __restrict__ out)
{
  __shared__ unsigned short smem[69888];
  const int W3B = 0, W4B = 26880, PB = 48384;

  const int t = threadIdx.x, l = t & 63, wv = t >> 6;
  const int lr = l & 15, lg = l >> 4;

  for (int j = t; j < 3200; j += 512){            // stage W3L
    int c = j / 20, k8 = j % 20;
    *(short8*)&smem[W3B + c*168 + k8*8] = *(const short8*)&W3t[c*160 + k8*8];
  }
  for (int j = t; j < 2560; j += 512){            // stage W4L
    int c = j / 20, k8 = j % 20;
    *(short8*)&smem[W4B + c*168 + k8*8] = *(const short8*)&W4t[c*160 + k8*8];
  }
  __syncthreads();

  unsigned short* patch = smem + PB + wv*2688;

  for (int it = 0; it < 4; ++it){
    const long chunk = ((long)blockIdx.x*8 + wv)*4 + it;
    const long n0 = chunk*16;

    // ---- B-frags from h2 ----
    short8 b[5];
    #pragma unroll
    for (int ks = 0; ks < 5; ++ks)
      b[ks] = *(const short8*)&h2[(n0 + lr)*160 + ks*32 + lg*8];

    // ---- L3 -> patch ----
    #pragma unroll
    for (int c = 0; c < 10; c += 2){
      short8 wa[5], wb[5];
      #pragma unroll
      for (int ks = 0; ks < 5; ++ks){
        wa[ks] = *(const short8*)&smem[W3B + (c*16 + lr)*168 + ks*32 + lg*8];
        wb[ks] = *(const short8*)&smem[W3B + ((c+1)*16 + lr)*168 + ks*32 + lg*8];
      }
      f32x4 aa = (f32x4){0.f,0.f,0.f,0.f};
      f32x4 ab = (f32x4){0.f,0.f,0.f,0.f};
      #pragma unroll
      for (int ks = 0; ks < 5; ++ks){
        aa = __builtin_amdgcn_mfma_f32_16x16x32_bf16(wa[ks], b[ks], aa, 0, 0, 0);
        ab = __builtin_amdgcn_mfma_f32_16x16x32_bf16(wb[ks], b[ks], ab, 0, 0, 0);
      }
      float4 va = *(const float4*)&b2p[c*16 + lg*4];
      float4 vb = *(const float4*)&b2p[(c+1)*16 + lg*4];
      float a0=fmaxf(aa[0]+va.x,0.f), a1=fmaxf(aa[1]+va.y,0.f),
            a2=fmaxf(aa[2]+va.z,0.f), a3=fmaxf(aa[3]+va.w,0.f);
      float b0=fmaxf(ab[0]+vb.x,0.f), b1=fmaxf(ab[1]+vb.y,0.f),
            b2=fmaxf(ab[2]+vb.z,0.f), b3=fmaxf(ab[3]+vb.w,0.f);
      ushort4 pa; pa.x=f2b(a0); pa.y=f2b(a1); pa.z=f2b(a2); pa.w=f2b(a3);
      ushort4 pb; pb.x=f2b(b0); pb.y=f2b(b1); pb.z=f2b(b2); pb.w=f2b(b3);
      *(ushort4*)&patch[lr*168 + c*16 + lg*4]     = pa;
      *(ushort4*)&patch[lr*168 + (c+1)*16 + lg*4] = pb;
    }

    // ---- L4: B from patch, f32 out ----
    short8 p4[5];
    #pragma unroll
    for (int ks = 0; ks < 5; ++ks)
      p4[ks] = *(const short8*)&patch[lr*168 + ks*32 + lg*8];
    #pragma unroll
    for (int c = 0; c < 8; c += 2){
      short8 wa[5], wb[5];
      #pragma unroll
      for (int ks = 0; ks < 5; ++ks){
        wa[ks] = *(const short8*)&smem[W4B + (c*16 + lr)*168 + ks*32 + lg*8];
        wb[ks] = *(const short8*)&smem[W4B + ((c+1)*16 + lr)*168 + ks*32 + lg*8];
      }
      f32x4 aa = (f32x4){0.f,0.f,0.f,0.f};
      f32x4 ab = (f32x4){0.f,0.f,0.f,0.f};
      #pragma unroll
      for (int ks = 0; ks < 5; ++ks){
        aa = __builtin_amdgcn_mfma_f32_16x16x32_bf16(wa[ks], p4[ks], aa, 0, 0, 0);
        ab = __builtin_amdgcn_mfma_f32_16x16x32_bf16(wb[ks], p4[ks], ab, 0, 0, 0);
      }
      float4 va = *(const float4*)&b3p[c*16 + lg*4];
      float4 vb = *(const float4*)&b3p[(c+1)*16 + lg*4];
      float4 oa; oa.x=aa[0]+va.x; oa.y=aa[1]+va.y; oa.z=aa[2]+va.z; oa.w=aa[3]+va.w;
      float4 ob; ob.x=ab[0]+vb.x; ob.y=ab[1]+vb.y; ob.z=ab[2]+vb.z; ob.w=ab[3]+vb.w;
      *(float4*)&out[(n0 + lr)*128 + c*16 + lg*4]     = oa;
      *(float4*)&out[(n0 + lr)*128 + (c+1)*16 + lg*4] = ob;
    }
  }
}

// ---------------- launch ----------------
extern "C" void kernel_launch(void* const* d_in, const int* in_sizes, int n_in,
                              void* d_out, int out_size, void* d_ws, size_t ws_size,
                              hipStream_t stream)
{
  const float* sig  = (const float*)d_in[0];
  const float* comp = (const float*)d_in[1];
  const float* Wm   = (const float*)d_in[2];
  const float* bm   = (const float*)d_in[3];
  const float* Wu   = (const float*)d_in[4];
  const float* bu   = (const float*)d_in[5];
  const float* W0   = (const float*)d_in[6];
  const float* b0   = (const float*)d_in[7];
  const float* W1   = (const float*)d_in[8];
  const float* b1   = (const float*)d_in[9];
  const float* W2   = (const float*)d_in[10];
  const float* b2   = (const float*)d_in[11];
  const float* W3   = (const float*)d_in[12];
  const float* b3   = (const float*)d_in[13];

  char* ws = (char*)d_ws;
  float* Wfold  = (float*)(ws + 0);
  float* bias_r = (float*)(ws + 65536);
  float* c0p    = (float*)(ws + 66048);
  float* b1p    = (float*)(ws + 66688);
  float* b2p    = (float*)(ws + 67328);
  float* b3p    = (float*)(ws + 67968);
  unsigned short* W1t = (unsigned short*)(ws + 69632);
  unsigned short* W2t = (unsigned short*)(ws + 151552);
  unsigned short* W3t = (unsigned short*)(ws + 202752);
  unsigned short* W4t = (unsigned short*)(ws + 253952);
  unsigned short* h2  = (unsigned short*)(ws + 524288);   // 262144*160*2 = 80 MiB

  prep1<<<129, 128, 0, stream>>>(Wm, Wu, bm, bu, Wfold, bias_r);
  prep2<<<443, 256, 0, stream>>>(W0, b0, W1, b1, W2, b2, W3, b3, Wfold, bias_r,
                                 W1t, W2t, W3t, W4t, c0p, b1p, b2p, b3p);
  pass12<<<512, 256, 0, stream>>>(sig, comp, W1t, W2t, c0p, b1p, h2);
  pass34<<<512, 512, 0, stream>>>(h2, W3t, W4t, b2p, b3p, (float*)d_out);
}